// Round 11
// baseline (109.793 us; speedup 1.0000x reference)
//
#include <hip/hip_runtime.h>

typedef unsigned short u16;
typedef unsigned int u32;
typedef __bf16 bf16;
typedef __bf16 bf16x8 __attribute__((ext_vector_type(8)));
typedef __bf16 bf16x4 __attribute__((ext_vector_type(4)));
typedef float f32x4 __attribute__((ext_vector_type(4)));

#define NSAMP 2048
#define KH 3
#define NNBR 16
#define F 128
#define OUT_O 256   // C_OUT * F_OUT
#define QT 384      // KH * F

// LDS row stride MUST be a multiple of 8 elems (16 B) — misaligned b128 LDS
// ops get split by HW (R7: stride 140 = 280 B tripled runtime). 136 = 272 B ok.
#define ZLD 136
#define YLD 136

__device__ __forceinline__ bf16x4 cvt4(float4 v) {
    bf16x4 h;
    h[0] = (bf16)v.x; h[1] = (bf16)v.y; h[2] = (bf16)v.z; h[3] = (bf16)v.w;
    return h;
}

__launch_bounds__(512, 4)
__global__ void featkhop(const float* __restrict__ xg,
                         const float* __restrict__ ng,
                         const float* __restrict__ Wg,
                         float* __restrict__ out) {
    // Zs rows 0..48 hold x + 48 neighbors (bf16). Rows 49..63 are read by MFMA
    // B-frags as don't-care garbage (their output rows are discarded); the f32
    // scratch arrays are aliased into that tail (3584 B of 4080 B). All writes
    // are barrier-ordered vs those reads, so reads are stable.
    __shared__ __align__(16) bf16 Zs[64 * ZLD];       // 17408 B
    __shared__ __align__(16) bf16 Ys[2][64 * YLD];    // 34816 B, double-buffered
    float* const xls = (float*)(Zs + 49 * ZLD);       // 128 f32 (13328 B offset, 16B-aligned)
    float* const sls = xls + F;                        // [3][128] f32
    float* const rsi = xls + 4 * F;                    // [3][128] f32: 1/(colsum+eps)

    const int i = blockIdx.x;
    const int t = threadIdx.x;
    const int lane = t & 63;
    const int w = t >> 6;        // wave 0..7
    const int lr = lane & 15;
    const int lg = lane >> 4;

    // ---- stage x: fp32 to xls, bf16 to Z row 0 ----
    if (t < F / 4) {
        float4 v = *(const float4*)(xg + (size_t)i * F + t * 4);
        *(float4*)(xls + t * 4) = v;
        *(bf16x4*)(Zs + 0 * ZLD + t * 4) = cvt4(v);
    }
    // ---- stage neighbors: bf16 rows 1..48 ----
    const float* nb = ng + (size_t)i * (KH * NNBR * F);
    {
        #pragma unroll
        for (int c = 0; c < 3; ++c) {
            int j = c * 512 + t;
            float4 v = *(const float4*)(nb + j * 4);
            int fl = j * 4;
            int row = 1 + (fl >> 7);     // neighbor 0..47 -> rows 1..48
            int b = fl & 127;
            *(bf16x4*)(Zs + row * ZLD + b) = cvt4(v);
        }
    }
    // ---- s[q][b] = sum_n nbr[q][n][b], read from GLOBAL f32 (L2-hot, no Zs dep) ----
    if (t < KH * F) {
        int q = t >> 7, b = t & 127;
        float s = 0.f;
        #pragma unroll
        for (int n = 0; n < NNBR; ++n) s += nb[(q * NNBR + n) * F + b];
        sls[q * F + b] = s;
    }
    __syncthreads();                     // bar 1: Zs/xls/sls ready

    const int a_row = w * 16 + lr;       // adjacency row this lane owns
    const float x_a = xls[a_row];
    const int cbase = lg * 8;            // within-32 col offset

    // ---- pre-pass: rowsum_q[a] (=colsum by symmetry) for ALL q; store rcp ----
    #pragma unroll
    for (int q = 0; q < KH; ++q) {
        const float s_a = sls[q * F + a_row];
        float ps = 0.f;
        #pragma unroll
        for (int kk = 0; kk < 4; ++kk) {
            float4 xb0 = *(const float4*)(xls + kk * 32 + cbase);
            float4 xb1 = *(const float4*)(xls + kk * 32 + cbase + 4);
            float4 sb0 = *(const float4*)(sls + q * F + kk * 32 + cbase);
            float4 sb1 = *(const float4*)(sls + q * F + kk * 32 + cbase + 4);
            float xb[8] = {xb0.x, xb0.y, xb0.z, xb0.w, xb1.x, xb1.y, xb1.z, xb1.w};
            float sb[8] = {sb0.x, sb0.y, sb0.z, sb0.w, sb1.x, sb1.y, sb1.z, sb1.w};
            #pragma unroll
            for (int e = 0; e < 8; ++e) {
                float tv = x_a * sb[e] + xb[e] * s_a;
                ps += __builtin_amdgcn_sqrtf(fmaxf(fabsf(tv), 1e-8f));
            }
        }
        ps += __shfl_xor(ps, 16);        // reduce over the 4 lg-mates
        ps += __shfl_xor(ps, 32);
        if (lg == 0) rsi[q * F + a_row] = __builtin_amdgcn_rcpf(ps + 1e-7f);
    }
    __syncthreads();                     // bar 2: rsi ready; scratch stable hereafter

    f32x4 acc2[4][2];
    {
        f32x4 zf = {0.f, 0.f, 0.f, 0.f};
        #pragma unroll
        for (int mt = 0; mt < 4; ++mt) { acc2[mt][0] = zf; acc2[mt][1] = zf; }
    }

    #pragma unroll
    for (int q = 0; q < KH; ++q) {
        // ---- build normalized bf16 A-fragments directly (no uv array) ----
        // (co-schedules with GEMM2(q-1)'s MFMAs in the unrolled stream)
        const float s_a = sls[q * F + a_row];
        bf16x8 afrag[4];
        #pragma unroll
        for (int kk = 0; kk < 4; ++kk) {
            float4 xb0 = *(const float4*)(xls + kk * 32 + cbase);
            float4 xb1 = *(const float4*)(xls + kk * 32 + cbase + 4);
            float4 sb0 = *(const float4*)(sls + q * F + kk * 32 + cbase);
            float4 sb1 = *(const float4*)(sls + q * F + kk * 32 + cbase + 4);
            float4 rb0 = *(const float4*)(rsi + q * F + kk * 32 + cbase);
            float4 rb1 = *(const float4*)(rsi + q * F + kk * 32 + cbase + 4);
            float xb[8] = {xb0.x, xb0.y, xb0.z, xb0.w, xb1.x, xb1.y, xb1.z, xb1.w};
            float sb[8] = {sb0.x, sb0.y, sb0.z, sb0.w, sb1.x, sb1.y, sb1.z, sb1.w};
            float rb[8] = {rb0.x, rb0.y, rb0.z, rb0.w, rb1.x, rb1.y, rb1.z, rb1.w};
            #pragma unroll
            for (int e = 0; e < 8; ++e) {
                float tv = x_a * sb[e] + xb[e] * s_a;
                float r = tv * __builtin_amdgcn_rsqf(fmaxf(fabsf(tv), 1e-8f));
                afrag[kk][e] = (bf16)(r * rb[e]);
            }
        }

        // ---- GEMM1 (swapped): Y^T = adj * Z^T ; adj frag is the A operand ----
        bf16* Ysb = Ys[q & 1];
        f32x4 acc1[4];
        {
            f32x4 zf = {0.f, 0.f, 0.f, 0.f};
            #pragma unroll
            for (int mt = 0; mt < 4; ++mt) acc1[mt] = zf;
        }
        #pragma unroll
        for (int kk = 0; kk < 4; ++kk) {
            #pragma unroll
            for (int mt = 0; mt < 4; ++mt) {
                bf16x8 zfrag = *(const bf16x8*)(Zs + (mt * 16 + lr) * ZLD + kk * 32 + cbase);
                acc1[mt] = __builtin_amdgcn_mfma_f32_16x16x32_bf16(afrag[kk], zfrag, acc1[mt], 0, 0, 0);
            }
        }

        // ---- W fragments for this q: load f32 from global (L2/L3-hot),
        //      convert in-register (element-wise: no address-of-vector-elem).
        //      Issued under the Y-store; drained by bar B's vmcnt. ----
        bf16x8 wf0[4], wf1[4];
        #pragma unroll
        for (int kk = 0; kk < 4; ++kk) {
            const float* wp = Wg + (size_t)(w * 32 + lr) * QT + q * F + kk * 32 + cbase;
            float4 a0 = *(const float4*)(wp);
            float4 a1 = *(const float4*)(wp + 4);
            float4 b0 = *(const float4*)(wp + 16 * QT);
            float4 b1 = *(const float4*)(wp + 16 * QT + 4);
            wf0[kk][0] = (bf16)a0.x; wf0[kk][1] = (bf16)a0.y;
            wf0[kk][2] = (bf16)a0.z; wf0[kk][3] = (bf16)a0.w;
            wf0[kk][4] = (bf16)a1.x; wf0[kk][5] = (bf16)a1.y;
            wf0[kk][6] = (bf16)a1.z; wf0[kk][7] = (bf16)a1.w;
            wf1[kk][0] = (bf16)b0.x; wf1[kk][1] = (bf16)b0.y;
            wf1[kk][2] = (bf16)b0.z; wf1[kk][3] = (bf16)b0.w;
            wf1[kk][4] = (bf16)b1.x; wf1[kk][5] = (bf16)b1.y;
            wf1[kk][6] = (bf16)b1.z; wf1[kk][7] = (bf16)b1.w;
        }

        // D: col = lr -> v_local, row = lg*4+r -> a_local => lane holds
        //    Y[v=mt*16+lr][a = w*16+lg*4+r], 4 consecutive a => b64 store.
        #pragma unroll
        for (int mt = 0; mt < 4; ++mt) {
            bf16x4 yv;
            #pragma unroll
            for (int r = 0; r < 4; ++r) yv[r] = (bf16)acc1[mt][r];
            *(bf16x4*)(Ysb + (mt * 16 + lr) * YLD + w * 16 + lg * 4) = yv;
        }
        __syncthreads();                 // bar B(q): Ys[q&1] complete

        // ---- GEMM2 (q-slice): acc2 += Y_q(64x128) @ Wq^T ----
        #pragma unroll
        for (int kk = 0; kk < 4; ++kk) {
            #pragma unroll
            for (int mt = 0; mt < 4; ++mt) {
                bf16x8 af = *(const bf16x8*)(Ysb + (mt * 16 + lr) * YLD + kk * 32 + cbase);
                acc2[mt][0] = __builtin_amdgcn_mfma_f32_16x16x32_bf16(af, wf0[kk], acc2[mt][0], 0, 0, 0);
                acc2[mt][1] = __builtin_amdgcn_mfma_f32_16x16x32_bf16(af, wf1[kk], acc2[mt][1], 0, 0, 0);
            }
        }
        // no trailing barrier needed: a wave can only reach the Ys[q&1] rewrite
        // at q+2 after passing bar B(q+1), which requires every wave to have
        // finished this GEMM2's reads.
    }

    // ---- epilogue: row 0 -> x_out, rows 1..48 -> nbr_out ----
    float* xout = out + (size_t)i * OUT_O;
    float* nout = out + (size_t)NSAMP * OUT_O + (size_t)i * 48 * OUT_O;
    #pragma unroll
    for (int mt = 0; mt < 4; ++mt) {
        #pragma unroll
        for (int r = 0; r < 4; ++r) {
            int v = mt * 16 + lg * 4 + r;
            #pragma unroll
            for (int nn = 0; nn < 2; ++nn) {
                int o = w * 32 + nn * 16 + lr;
                float val = acc2[mt][nn][r];
                if (v == 0) xout[o] = val;
                else if (v <= 48) nout[(size_t)(v - 1) * OUT_O + o] = val;
            }
        }
    }
}

extern "C" void kernel_launch(void* const* d_in, const int* in_sizes, int n_in,
                              void* d_out, int out_size, void* d_ws, size_t ws_size,
                              hipStream_t stream) {
    const float* x   = (const float*)d_in[0];
    const float* nbr = (const float*)d_in[1];
    const float* W   = (const float*)d_in[2];
    featkhop<<<NSAMP, 512, 0, stream>>>(x, nbr, W, (float*)d_out);
}

// Round 12
// 95.848 us; speedup vs baseline: 1.1455x; 1.1455x over previous
//
#include <hip/hip_runtime.h>

typedef unsigned short u16;
typedef unsigned int u32;
typedef __bf16 bf16;
typedef __bf16 bf16x8 __attribute__((ext_vector_type(8)));
typedef __bf16 bf16x4 __attribute__((ext_vector_type(4)));
typedef float f32x4 __attribute__((ext_vector_type(4)));

#define NSAMP 2048
#define KH 3
#define NNBR 16
#define F 128
#define OUT_O 256   // C_OUT * F_OUT
#define QT 384      // KH * F

// LDS row stride MUST be a multiple of 8 elems (16 B) — misaligned b128 LDS
// ops get split by HW (R7: stride 140 = 280 B tripled runtime). 136 = 272 B ok.
#define ZLD 136
#define YLD 136

__device__ __forceinline__ bf16x4 cvt4(float4 v) {
    bf16x4 h;
    h[0] = (bf16)v.x; h[1] = (bf16)v.y; h[2] = (bf16)v.z; h[3] = (bf16)v.w;
    return h;
}

__global__ void wprep(const float* __restrict__ W, bf16* __restrict__ Wbf) {
    int i = blockIdx.x * 256 + threadIdx.x;
    if (i < OUT_O * QT) Wbf[i] = (bf16)W[i];
}

// Register budget is the whole game: total (VGPR+AGPR) <= 85 gives 24 waves/CU
// (3 blocks) since LDS (52224B) already fits 3/CU. Hence: uvh kept as bf16
// (16 regs), GEMM1 acc1 is a single f32x4, W loaded inside GEMM2 (no 32-reg
// prefetch), rolled q-loop.
__launch_bounds__(512, 6)
__global__ void featkhop(const float* __restrict__ xg,
                         const float* __restrict__ ng,
                         const bf16* __restrict__ Wbf,
                         float* __restrict__ out) {
    // Zs rows 0..48 hold x + 48 neighbors (bf16). Rows 49..63 are read by MFMA
    // B-frags as don't-care garbage (their output rows are discarded); the f32
    // scratch arrays are aliased into that tail. All writes are barrier-ordered
    // vs those reads, so reads are stable.
    __shared__ __align__(16) bf16 Zs[64 * ZLD];       // 17408 B
    __shared__ __align__(16) bf16 Ys[2][64 * YLD];    // 34816 B, double-buffered
    float* const xls = (float*)(Zs + 49 * ZLD);       // 128 f32 (13328 B offset, 16B-aligned)
    float* const sls = xls + F;                        // [3][128] f32
    float* const rsi = xls + 4 * F;                    // 128 f32: 1/(colsum+eps), per current q

    const int i = blockIdx.x;
    const int t = threadIdx.x;
    const int lane = t & 63;
    const int w = t >> 6;        // wave 0..7
    const int lr = lane & 15;
    const int lg = lane >> 4;

    // ---- stage x: fp32 to xls, bf16 to Z row 0 ----
    if (t < F / 4) {
        float4 v = *(const float4*)(xg + (size_t)i * F + t * 4);
        *(float4*)(xls + t * 4) = v;
        *(bf16x4*)(Zs + 0 * ZLD + t * 4) = cvt4(v);
    }
    // ---- stage neighbors: bf16 rows 1..48 ----
    const float* nb = ng + (size_t)i * (KH * NNBR * F);
    {
        #pragma unroll
        for (int c = 0; c < 3; ++c) {
            int j = c * 512 + t;
            float4 v = *(const float4*)(nb + j * 4);
            int fl = j * 4;
            int row = 1 + (fl >> 7);     // neighbor 0..47 -> rows 1..48
            int b = fl & 127;
            *(bf16x4*)(Zs + row * ZLD + b) = cvt4(v);
        }
    }
    // ---- s[q][b] = sum_n nbr[q][n][b], from GLOBAL f32 (L2-hot, no Zs dep) ----
    if (t < KH * F) {
        int q = t >> 7, b = t & 127;
        float s = 0.f;
        #pragma unroll
        for (int n = 0; n < NNBR; ++n) s += nb[(q * NNBR + n) * F + b];
        sls[q * F + b] = s;
    }
    __syncthreads();                     // bar 1: Zs/xls/sls ready

    const int a_row = w * 16 + lr;       // adjacency row this lane owns
    const float x_a = xls[a_row];
    const int cbase = lg * 8;            // within-32 col offset

    f32x4 acc2[4][2];
    {
        f32x4 zf = {0.f, 0.f, 0.f, 0.f};
        #pragma unroll
        for (int mt = 0; mt < 4; ++mt) { acc2[mt][0] = zf; acc2[mt][1] = zf; }
    }

    for (int q = 0; q < KH; ++q) {       // rolled: register pressure control
        // ---- build unscaled u-row as bf16 (16 regs); rowsum in f32 ----
        const float s_a = sls[q * F + a_row];
        bf16x8 uvh[4];
        float ps = 0.f;
        #pragma unroll
        for (int kk = 0; kk < 4; ++kk) {
            float4 xb0 = *(const float4*)(xls + kk * 32 + cbase);
            float4 xb1 = *(const float4*)(xls + kk * 32 + cbase + 4);
            float4 sb0 = *(const float4*)(sls + q * F + kk * 32 + cbase);
            float4 sb1 = *(const float4*)(sls + q * F + kk * 32 + cbase + 4);
            float xb[8] = {xb0.x, xb0.y, xb0.z, xb0.w, xb1.x, xb1.y, xb1.z, xb1.w};
            float sb[8] = {sb0.x, sb0.y, sb0.z, sb0.w, sb1.x, sb1.y, sb1.z, sb1.w};
            #pragma unroll
            for (int e = 0; e < 8; ++e) {
                float tv = x_a * sb[e] + xb[e] * s_a;
                float r = tv * __builtin_amdgcn_rsqf(fmaxf(fabsf(tv), 1e-8f));
                uvh[kk][e] = (bf16)r;
                ps += fabsf(r);
            }
        }
        ps += __shfl_xor(ps, 16);        // reduce over the 4 lg-mates
        ps += __shfl_xor(ps, 32);
        if (lg == 0) rsi[a_row] = __builtin_amdgcn_rcpf(ps + 1e-7f);
        __syncthreads();                 // bar A(q): rsi ready; Ys[q&1] free

        // ---- scale to normalized A-fragments (double-rounded bf16; margin 4x) ----
        bf16x8 afrag[4];
        #pragma unroll
        for (int kk = 0; kk < 4; ++kk) {
            float4 r0 = *(const float4*)(rsi + kk * 32 + cbase);
            float4 r1 = *(const float4*)(rsi + kk * 32 + cbase + 4);
            float rb[8] = {r0.x, r0.y, r0.z, r0.w, r1.x, r1.y, r1.z, r1.w};
            #pragma unroll
            for (int e = 0; e < 8; ++e)
                afrag[kk][e] = (bf16)((float)uvh[kk][e] * rb[e]);
        }

        // ---- GEMM1 (swapped): Y^T = adj * Z^T, mt-outer, single f32x4 acc ----
        bf16* Ysb = Ys[q & 1];
        #pragma unroll
        for (int mt = 0; mt < 4; ++mt) {
            f32x4 a1 = {0.f, 0.f, 0.f, 0.f};
            #pragma unroll
            for (int kk = 0; kk < 4; ++kk) {
                bf16x8 zfrag = *(const bf16x8*)(Zs + (mt * 16 + lr) * ZLD + kk * 32 + cbase);
                a1 = __builtin_amdgcn_mfma_f32_16x16x32_bf16(afrag[kk], zfrag, a1, 0, 0, 0);
            }
            // D: col=lr -> v_local, row=lg*4+r -> a_local => lane holds
            // Y[v=mt*16+lr][a=w*16+lg*4+r], 4 consecutive a => b64 store.
            bf16x4 yv;
            #pragma unroll
            for (int r = 0; r < 4; ++r) yv[r] = (bf16)a1[r];
            *(bf16x4*)(Ysb + (mt * 16 + lr) * YLD + w * 16 + lg * 4) = yv;
        }
        __syncthreads();                 // bar B(q): Ys[q&1] complete

        // ---- GEMM2 (q-slice): acc2 += Y_q(64x128) @ Wq^T; W loaded in-loop
        //      (L2-resident bf16; no 32-reg prefetch) ----
        #pragma unroll
        for (int kk = 0; kk < 4; ++kk) {
            const bf16* wp = Wbf + (size_t)(w * 32 + lr) * QT + q * F + kk * 32 + cbase;
            bf16x8 wf0 = *(const bf16x8*)wp;
            bf16x8 wf1 = *(const bf16x8*)(wp + 16 * QT);
            #pragma unroll
            for (int mt = 0; mt < 4; ++mt) {
                bf16x8 af = *(const bf16x8*)(Ysb + (mt * 16 + lr) * YLD + kk * 32 + cbase);
                acc2[mt][0] = __builtin_amdgcn_mfma_f32_16x16x32_bf16(af, wf0, acc2[mt][0], 0, 0, 0);
                acc2[mt][1] = __builtin_amdgcn_mfma_f32_16x16x32_bf16(af, wf1, acc2[mt][1], 0, 0, 0);
            }
        }
        // no trailing barrier: rsi(q+1) write and Ys[(q+1)&1] writes are
        // ordered after bar A(q+1)/B(q+1), which require every wave to have
        // finished this GEMM2's reads.
    }

    // ---- epilogue: row 0 -> x_out, rows 1..48 -> nbr_out ----
    float* xout = out + (size_t)i * OUT_O;
    float* nout = out + (size_t)NSAMP * OUT_O + (size_t)i * 48 * OUT_O;
    #pragma unroll
    for (int mt = 0; mt < 4; ++mt) {
        #pragma unroll
        for (int r = 0; r < 4; ++r) {
            int v = mt * 16 + lg * 4 + r;
            #pragma unroll
            for (int nn = 0; nn < 2; ++nn) {
                int o = w * 32 + nn * 16 + lr;
                float val = acc2[mt][nn][r];
                if (v == 0) xout[o] = val;
                else if (v <= 48) nout[(size_t)(v - 1) * OUT_O + o] = val;
            }
        }
    }
}

extern "C" void kernel_launch(void* const* d_in, const int* in_sizes, int n_in,
                              void* d_out, int out_size, void* d_ws, size_t ws_size,
                              hipStream_t stream) {
    const float* x   = (const float*)d_in[0];
    const float* nbr = (const float*)d_in[1];
    const float* W   = (const float*)d_in[2];
    bf16* Wbf = (bf16*)d_ws;   // 256*384 bf16 = 192 KiB
    wprep<<<(OUT_O * QT + 255) / 256, 256, 0, stream>>>(W, Wbf);
    featkhop<<<NSAMP, 512, 0, stream>>>(x, nbr, Wbf, (float*)d_out);
}

// Round 13
// 93.163 us; speedup vs baseline: 1.1785x; 1.0288x over previous
//
#include <hip/hip_runtime.h>

typedef unsigned short u16;
typedef unsigned int u32;
typedef __bf16 bf16;
typedef __bf16 bf16x8 __attribute__((ext_vector_type(8)));
typedef __bf16 bf16x4 __attribute__((ext_vector_type(4)));
typedef float f32x4 __attribute__((ext_vector_type(4)));

#define NSAMP 2048
#define KH 3
#define NNBR 16
#define F 128
#define OUT_O 256   // C_OUT * F_OUT
#define QT 384      // KH * F

// LDS row stride MUST be a multiple of 8 elems (16 B) — misaligned b128 LDS
// ops get split by HW (R7: stride 140 = 280 B tripled runtime). 136 = 272 B ok.
#define ZLD 136
#define YLD 136

__device__ __forceinline__ bf16x4 cvt4(float4 v) {
    bf16x4 h;
    h[0] = (bf16)v.x; h[1] = (bf16)v.y; h[2] = (bf16)v.z; h[3] = (bf16)v.w;
    return h;
}

__global__ void wprep(const float* __restrict__ W, bf16* __restrict__ Wbf) {
    int i = blockIdx.x * 256 + threadIdx.x;
    if (i < OUT_O * QT) Wbf[i] = (bf16)W[i];
}

// ---- pipeline stages as forceinline helpers (constant indices after inline) ----

__device__ __forceinline__ void build_row(int q, const float* xls, const float* sls,
                                          float* rsb, bf16x8 uvh[4],
                                          float x_a, int a_row, int cbase, int lg) {
    const float s_a = sls[q * F + a_row];
    float ps = 0.f;
    #pragma unroll
    for (int kk = 0; kk < 4; ++kk) {
        float4 xb0 = *(const float4*)(xls + kk * 32 + cbase);
        float4 xb1 = *(const float4*)(xls + kk * 32 + cbase + 4);
        float4 sb0 = *(const float4*)(sls + q * F + kk * 32 + cbase);
        float4 sb1 = *(const float4*)(sls + q * F + kk * 32 + cbase + 4);
        float xb[8] = {xb0.x, xb0.y, xb0.z, xb0.w, xb1.x, xb1.y, xb1.z, xb1.w};
        float sb[8] = {sb0.x, sb0.y, sb0.z, sb0.w, sb1.x, sb1.y, sb1.z, sb1.w};
        #pragma unroll
        for (int e = 0; e < 8; ++e) {
            float tv = x_a * sb[e] + xb[e] * s_a;
            float r = tv * __builtin_amdgcn_rsqf(fmaxf(fabsf(tv), 1e-8f));
            uvh[kk][e] = (bf16)r;               // bf16 keeps cross-barrier liveness at 16 regs
            ps += fabsf(r);
        }
    }
    ps += __shfl_xor(ps, 16);                    // reduce over the 4 lg-mates
    ps += __shfl_xor(ps, 32);
    if (lg == 0) rsb[a_row] = __builtin_amdgcn_rcpf(ps + 1e-7f);
}

__device__ __forceinline__ void gemm1_store(const bf16x8 uvh[4], const float* rsb,
                                            const bf16* Zs, bf16* Ysb,
                                            int lr, int lg, int w, int cbase) {
    bf16x8 afrag[4];
    #pragma unroll
    for (int kk = 0; kk < 4; ++kk) {
        float4 r0 = *(const float4*)(rsb + kk * 32 + cbase);
        float4 r1 = *(const float4*)(rsb + kk * 32 + cbase + 4);
        float rb[8] = {r0.x, r0.y, r0.z, r0.w, r1.x, r1.y, r1.z, r1.w};
        #pragma unroll
        for (int e = 0; e < 8; ++e)
            afrag[kk][e] = (bf16)((float)uvh[kk][e] * rb[e]);
    }
    f32x4 acc1[4];
    {
        f32x4 zf = {0.f, 0.f, 0.f, 0.f};
        #pragma unroll
        for (int mt = 0; mt < 4; ++mt) acc1[mt] = zf;
    }
    #pragma unroll
    for (int kk = 0; kk < 4; ++kk) {
        #pragma unroll
        for (int mt = 0; mt < 4; ++mt) {
            bf16x8 zfrag = *(const bf16x8*)(Zs + (mt * 16 + lr) * ZLD + kk * 32 + cbase);
            acc1[mt] = __builtin_amdgcn_mfma_f32_16x16x32_bf16(afrag[kk], zfrag, acc1[mt], 0, 0, 0);
        }
    }
    // D: col=lr -> v_local, row=lg*4+r -> a_local => lane holds
    // Y[v=mt*16+lr][a=w*16+lg*4+r], 4 consecutive a => b64 store.
    #pragma unroll
    for (int mt = 0; mt < 4; ++mt) {
        bf16x4 yv;
        #pragma unroll
        for (int r = 0; r < 4; ++r) yv[r] = (bf16)acc1[mt][r];
        *(bf16x4*)(Ysb + (mt * 16 + lr) * YLD + w * 16 + lg * 4) = yv;
    }
}

__device__ __forceinline__ void gemm2_acc(const bf16* Wq, const bf16* Ysb,
                                          f32x4 acc2[4][2], int lr, int cbase) {
    #pragma unroll
    for (int kk = 0; kk < 4; ++kk) {
        bf16x8 wf0 = *(const bf16x8*)(Wq + kk * 32 + cbase);
        bf16x8 wf1 = *(const bf16x8*)(Wq + 16 * QT + kk * 32 + cbase);
        #pragma unroll
        for (int mt = 0; mt < 4; ++mt) {
            bf16x8 af = *(const bf16x8*)(Ysb + (mt * 16 + lr) * YLD + kk * 32 + cbase);
            acc2[mt][0] = __builtin_amdgcn_mfma_f32_16x16x32_bf16(af, wf0, acc2[mt][0], 0, 0, 0);
            acc2[mt][1] = __builtin_amdgcn_mfma_f32_16x16x32_bf16(af, wf1, acc2[mt][1], 0, 0, 0);
        }
    }
}

// Software-pipelined: region(q) = GEMM2(q-1) || scale+GEMM1(q) || build(q+1),
// ONE barrier per region (5 total vs R8's 7). rsi double-buffered; Ys ping-pong.
__launch_bounds__(512, 4)
__global__ void featkhop(const float* __restrict__ xg,
                         const float* __restrict__ ng,
                         const bf16* __restrict__ Wbf,
                         float* __restrict__ out) {
    // Zs rows 0..48 hold x + 48 neighbors (bf16). Rows 49..63 are read by MFMA
    // B-frags as don't-care garbage (their output rows are discarded); the f32
    // scratch arrays alias that tail (3072 B of 4080 B), barrier-ordered.
    __shared__ __align__(16) bf16 Zs[64 * ZLD];       // 17408 B
    __shared__ __align__(16) bf16 Ys[2][64 * YLD];    // 34816 B, ping-pong
    float* const xls  = (float*)(Zs + 49 * ZLD);      // 128 f32 (byte 13328, 16B-aligned)
    float* const sls  = xls + F;                       // [3][128] f32
    float* const rsi0 = xls + 4 * F;                   // 128 f32
    float* const rsi1 = xls + 5 * F;                   // 128 f32

    const int i = blockIdx.x;
    const int t = threadIdx.x;
    const int lane = t & 63;
    const int w = t >> 6;        // wave 0..7
    const int lr = lane & 15;
    const int lg = lane >> 4;

    // ---- stage x: fp32 to xls, bf16 to Z row 0 ----
    if (t < F / 4) {
        float4 v = *(const float4*)(xg + (size_t)i * F + t * 4);
        *(float4*)(xls + t * 4) = v;
        *(bf16x4*)(Zs + 0 * ZLD + t * 4) = cvt4(v);
    }
    // ---- stage neighbors: bf16 rows 1..48 ----
    const float* nb = ng + (size_t)i * (KH * NNBR * F);
    {
        #pragma unroll
        for (int c = 0; c < 3; ++c) {
            int j = c * 512 + t;
            float4 v = *(const float4*)(nb + j * 4);
            int fl = j * 4;
            int row = 1 + (fl >> 7);     // neighbor 0..47 -> rows 1..48
            int b = fl & 127;
            *(bf16x4*)(Zs + row * ZLD + b) = cvt4(v);
        }
    }
    // ---- s[q][b] = sum_n nbr[q][n][b], from GLOBAL f32 (L2-hot, no Zs dep) ----
    if (t < KH * F) {
        int q = t >> 7, b = t & 127;
        float s = 0.f;
        #pragma unroll
        for (int n = 0; n < NNBR; ++n) s += nb[(q * NNBR + n) * F + b];
        sls[q * F + b] = s;
    }
    __syncthreads();                     // bar S: Zs/xls/sls ready

    const int a_row = w * 16 + lr;
    const float x_a = xls[a_row];
    const int cbase = lg * 8;
    const bf16* Wbase = Wbf + (size_t)(w * 32 + lr) * QT;

    f32x4 acc2[4][2];
    {
        f32x4 zf = {0.f, 0.f, 0.f, 0.f};
        #pragma unroll
        for (int mt = 0; mt < 4; ++mt) { acc2[mt][0] = zf; acc2[mt][1] = zf; }
    }

    bf16x8 uvh[4];

    // ---- prologue: build(0) ----
    build_row(0, xls, sls, rsi0, uvh, x_a, a_row, cbase, lg);
    __syncthreads();                     // bar P: rsi0 ready

    // ---- region 0: GEMM1(0) ; build(1) ----
    gemm1_store(uvh, rsi0, Zs, Ys[0], lr, lg, w, cbase);
    build_row(1, xls, sls, rsi1, uvh, x_a, a_row, cbase, lg);
    __syncthreads();                     // bar 0: Ys[0], rsi1 ready

    // ---- region 1: GEMM2(0) ; GEMM1(1) ; build(2) ----
    gemm2_acc(Wbase + 0 * F, Ys[0], acc2, lr, cbase);
    gemm1_store(uvh, rsi1, Zs, Ys[1], lr, lg, w, cbase);
    build_row(2, xls, sls, rsi0, uvh, x_a, a_row, cbase, lg);  // rsi0 readers were region 0
    __syncthreads();                     // bar 1: Ys[1], rsi0(q2) ready

    // ---- region 2: GEMM2(1) ; GEMM1(2) ----
    gemm2_acc(Wbase + 1 * F, Ys[1], acc2, lr, cbase);
    gemm1_store(uvh, rsi0, Zs, Ys[0], lr, lg, w, cbase);       // Ys[0] readers were region 1
    __syncthreads();                     // bar 2: Ys[0](q2) ready

    // ---- tail: GEMM2(2) ----
    gemm2_acc(Wbase + 2 * F, Ys[0], acc2, lr, cbase);

    // ---- epilogue: row 0 -> x_out, rows 1..48 -> nbr_out ----
    float* xout = out + (size_t)i * OUT_O;
    float* nout = out + (size_t)NSAMP * OUT_O + (size_t)i * 48 * OUT_O;
    #pragma unroll
    for (int mt = 0; mt < 4; ++mt) {
        #pragma unroll
        for (int r = 0; r < 4; ++r) {
            int v = mt * 16 + lg * 4 + r;
            #pragma unroll
            for (int nn = 0; nn < 2; ++nn) {
                int o = w * 32 + nn * 16 + lr;
                float val = acc2[mt][nn][r];
                if (v == 0) xout[o] = val;
                else if (v <= 48) nout[(size_t)(v - 1) * OUT_O + o] = val;
            }
        }
    }
}

extern "C" void kernel_launch(void* const* d_in, const int* in_sizes, int n_in,
                              void* d_out, int out_size, void* d_ws, size_t ws_size,
                              hipStream_t stream) {
    const float* x   = (const float*)d_in[0];
    const float* nbr = (const float*)d_in[1];
    const float* W   = (const float*)d_in[2];
    bf16* Wbf = (bf16*)d_ws;   // 256*384 bf16 = 192 KiB
    wprep<<<(OUT_O * QT + 255) / 256, 256, 0, stream>>>(W, Wbf);
    featkhop<<<NSAMP, 512, 0, stream>>>(x, nbr, Wbf, (float*)d_out);
}